// Round 1
// baseline (370.323 us; speedup 1.0000x reference)
//
#include <hip/hip_runtime.h>
#include <math.h>

// Problem constants (fixed by setup_inputs)
constexpr int nB = 16, nA = 3, nH = 128, nW = 128, nC = 80;
constexpr int HW   = nH * nW;          // 16384
constexpr int NPOS = nB * nA * HW;     // 786432

__device__ __forceinline__ float sigmoidf_fast(float x) {
    return 1.0f / (1.0f + __expf(-x));
}

__global__ __launch_bounds__(256) void yolo_decode_kernel(
    const float* __restrict__ t_xywha,   // [nB,nA,nH,nW,5]
    const float* __restrict__ conf,      // [nB,nA,nH,nW,1]
    const float* __restrict__ cls,       // [nB,nA,nH,nW,80]
    const float* __restrict__ anchors,   // [nA,2]
    float* __restrict__ out)             // [NPOS*5 | NPOS | NPOS]
{
    const int hw = blockIdx.x * 256 + threadIdx.x;   // h*nW + w
    const int ba = blockIdx.y;                        // b*nA + a
    const int a  = ba % nA;
    const int h  = hw >> 7;           // nW = 128
    const int w  = hw & 127;

    const long long p = (long long)ba * HW + hw;      // flat position

    // ---- class max / argmax over 80 logits (sigmoid is monotone) ----
    const float4* __restrict__ c4 = (const float4*)(cls + p * nC); // 320B-aligned
    float m = -INFINITY;
    int idx = 0;
#pragma unroll
    for (int i = 0; i < nC / 4; ++i) {
        float4 v = c4[i];
        if (v.x > m) { m = v.x; idx = 4 * i + 0; }
        if (v.y > m) { m = v.y; idx = 4 * i + 1; }
        if (v.z > m) { m = v.z; idx = 4 * i + 2; }
        if (v.w > m) { m = v.w; idx = 4 * i + 3; }
    }

    // ---- box decode ----
    const float* tp = t_xywha + p * 5;   // 20B stride: scalar loads
    const float tx = tp[0], ty = tp[1], tw = tp[2], th = tp[3], ta = tp[4];

    const float aw = anchors[a * 2 + 0];
    const float ah = anchors[a * 2 + 1];

    const float px   = (sigmoidf_fast(tx) + (float)w) * 8.0f;   // STRIDE = 8
    const float py   = (sigmoidf_fast(ty) + (float)h) * 8.0f;
    const float pw   = __expf(tw) * aw;
    const float ph   = __expf(th) * ah;
    // sigmoid(ta)*2pi - pi, then /pi*180  == sigmoid(ta)*360 - 180
    const float pdeg = sigmoidf_fast(ta) * 360.0f - 180.0f;

    const float cf = sigmoidf_fast(conf[p]) * sigmoidf_fast(m);

    // ---- stores ----
    float* op = out + p * 5;
    op[0] = px; op[1] = py; op[2] = pw; op[3] = ph; op[4] = pdeg;

    out[(long long)NPOS * 5 + p] = (float)idx;   // cls_idx as f32
    out[(long long)NPOS * 6 + p] = cf;           // confs
}

extern "C" void kernel_launch(void* const* d_in, const int* in_sizes, int n_in,
                              void* d_out, int out_size, void* d_ws, size_t ws_size,
                              hipStream_t stream) {
    const float* t_xywha = (const float*)d_in[0];
    const float* conf    = (const float*)d_in[1];
    const float* cls     = (const float*)d_in[2];
    const float* anchors = (const float*)d_in[3];
    float* out = (float*)d_out;

    dim3 grid(HW / 256, nB * nA);   // (64, 48)
    dim3 block(256);
    yolo_decode_kernel<<<grid, block, 0, stream>>>(t_xywha, conf, cls, anchors, out);
}

// Round 2
// 360.416 us; speedup vs baseline: 1.0275x; 1.0275x over previous
//
#include <hip/hip_runtime.h>
#include <math.h>

// Problem constants (fixed by setup_inputs)
constexpr int nB = 16, nA = 3, nH = 128, nW = 128, nC = 80;
constexpr int HW = nH * nW;                       // 16384
constexpr long long NPOS = (long long)nB * nA * HW; // 786432

__device__ __forceinline__ float sigmoidf_fast(float x) {
    return 1.0f / (1.0f + __expf(-x));
}

__global__ __launch_bounds__(256) void yolo_decode_kernel(
    const float* __restrict__ t_xywha,   // [nB,nA,nH,nW,5]
    const float* __restrict__ conf,      // [nB,nA,nH,nW,1]
    const float* __restrict__ cls,       // [nB,nA,nH,nW,80]
    const float* __restrict__ anchors,   // [nA,2]
    float* __restrict__ out)             // [NPOS*5 | NPOS | NPOS]
{
    const int tid  = threadIdx.x;
    const int lane = tid & 63;
    const int hwBlock = blockIdx.x * 256;
    const int ba = blockIdx.y;            // b*nA + a
    const int a  = ba % nA;

    const long long blockPos = (long long)ba * HW + hwBlock;
    const long long wavePos  = blockPos + (tid & ~63);   // wave's first position

    // ---- phase 1: cls max/argmax, 4 lanes cooperate per position ----
    // Per pass: 16 positions/wave; lane j of group g reads float4s j,j+4,..,j+16
    // of position (wavePos + k*16 + g). Each instruction = 16 x 64B contiguous
    // chunks; a pass consumes 5KB contiguous with full line reuse.
    const int g = lane >> 2;               // 0..15
    const int j = lane & 3;                // 0..3
    const int myPass    = lane >> 4;       // pass that computes my position
    const int mySrcLane = (lane & 15) << 2;

    float myM = -INFINITY; int myIdx = 0;

    #pragma unroll
    for (int k = 0; k < 4; ++k) {
        const long long p = wavePos + k * 16 + g;
        const float4* __restrict__ c4 = (const float4*)(cls + p * nC);
        float m = -INFINITY; int idx = 0;
        #pragma unroll
        for (int i = 0; i < 5; ++i) {
            const float4 v = c4[j + 4 * i];
            const int base = 4 * (j + 4 * i);
            if (v.x > m) { m = v.x; idx = base + 0; }
            if (v.y > m) { m = v.y; idx = base + 1; }
            if (v.z > m) { m = v.z; idx = base + 2; }
            if (v.w > m) { m = v.w; idx = base + 3; }
        }
        // butterfly across the 4 sub-lanes (first-occurrence tiebreak)
        #pragma unroll
        for (int d = 1; d <= 2; d <<= 1) {
            const float om = __shfl_xor(m, d);
            const int   oi = __shfl_xor(idx, d);
            if (om > m || (om == m && oi < idx)) { m = om; idx = oi; }
        }
        // redistribute: lane l owns position wavePos + l, produced in pass l>>4
        const float rm = __shfl(m, mySrcLane);
        const int   ri = __shfl(idx, mySrcLane);
        if (myPass == k) { myM = rm; myIdx = ri; }
    }

    // ---- phase 2: one thread per position ----
    const long long q = blockPos + tid;
    const int hw = hwBlock + tid;
    const int h = hw >> 7;        // nW = 128
    const int w = hw & 127;

    const float* tp = t_xywha + q * 5;
    const float tx = tp[0], ty = tp[1], tw = tp[2], th = tp[3], ta = tp[4];

    const float aw = anchors[a * 2 + 0];
    const float ah = anchors[a * 2 + 1];

    const float px   = (sigmoidf_fast(tx) + (float)w) * 8.0f;  // STRIDE = 8
    const float py   = (sigmoidf_fast(ty) + (float)h) * 8.0f;
    const float pw   = __expf(tw) * aw;
    const float ph   = __expf(th) * ah;
    const float pdeg = sigmoidf_fast(ta) * 360.0f - 180.0f;    // sig*2pi-pi -> deg

    const float cf = sigmoidf_fast(conf[q]) * sigmoidf_fast(myM);

    float* op = out + q * 5;
    op[0] = px; op[1] = py; op[2] = pw; op[3] = ph; op[4] = pdeg;

    out[NPOS * 5 + q] = (float)myIdx;   // cls_idx as f32
    out[NPOS * 6 + q] = cf;             // confs
}

extern "C" void kernel_launch(void* const* d_in, const int* in_sizes, int n_in,
                              void* d_out, int out_size, void* d_ws, size_t ws_size,
                              hipStream_t stream) {
    const float* t_xywha = (const float*)d_in[0];
    const float* conf    = (const float*)d_in[1];
    const float* cls     = (const float*)d_in[2];
    const float* anchors = (const float*)d_in[3];
    float* out = (float*)d_out;

    dim3 grid(HW / 256, nB * nA);   // (64, 48)
    dim3 block(256);
    yolo_decode_kernel<<<grid, block, 0, stream>>>(t_xywha, conf, cls, anchors, out);
}

// Round 3
// 358.271 us; speedup vs baseline: 1.0336x; 1.0060x over previous
//
#include <hip/hip_runtime.h>
#include <math.h>

// Problem constants (fixed by setup_inputs)
constexpr int nB = 16, nA = 3, nH = 128, nW = 128, nC = 80;
constexpr int HW = nH * nW;                 // 16384
constexpr int NPOS = nB * nA * HW;          // 786432  (fits int)
constexpr int TPB = 128;                    // threads/block == positions/block
constexpr int SEG = 20;                     // float4 segments per 80-float cls row
constexpr int PAD = 21;                     // padded LDS row stride (21 coprime 32)

__device__ __forceinline__ float sigmoidf_fast(float x) {
    return 1.0f / (1.0f + __expf(-x));
}

__global__ __launch_bounds__(TPB) void yolo_decode_kernel(
    const float* __restrict__ t_xywha,   // [NPOS,5]
    const float* __restrict__ conf,      // [NPOS]
    const float* __restrict__ cls,       // [NPOS,80]
    const float* __restrict__ anchors,   // [nA,2]
    float* __restrict__ out)             // [NPOS*5 | NPOS | NPOS]
{
    __shared__ float pm[TPB * PAD];      // per-(pos,segment) partial max
    __shared__ int   pi[TPB * PAD];      // per-(pos,segment) partial argmax
    __shared__ float txy[TPB * 5];       // staging for t_xywha rows / p_xywha rows

    const int t    = threadIdx.x;
    const int base = blockIdx.x * TPB;   // block's first position

    // ---- phase A: fully contiguous cls loads; per-float4 partials -> LDS ----
    // float4 f = t + 128*i  ->  position p = f/20, segment s = f%20 (incremental)
    const float4* __restrict__ c4 = (const float4*)(cls + (long long)base * nC);
    int p = t / 20, s = t % 20;
    #pragma unroll
    for (int i = 0; i < SEG; ++i) {
        const float4 v = c4[t + TPB * i];
        float m = v.x; int id = 4 * s;
        if (v.y > m) { m = v.y; id = 4 * s + 1; }
        if (v.z > m) { m = v.z; id = 4 * s + 2; }
        if (v.w > m) { m = v.w; id = 4 * s + 3; }
        pm[p * PAD + s] = m;             // write: consecutive words, conflict-free
        pi[p * PAD + s] = id;
        p += 6; s += 8; if (s >= 20) { s -= 20; p += 1; }   // f += 128
    }

    // stage t_xywha rows (independent of partials; before the same barrier)
    const float* __restrict__ txyg = t_xywha + (long long)base * 5;
    #pragma unroll
    for (int i = 0; i < 5; ++i) txy[t + TPB * i] = txyg[t + TPB * i];

    __syncthreads();

    // ---- phase B: combine 20 partials (s ascending => first-occurrence argmax) ----
    float m = -INFINITY; int idx = 0;
    #pragma unroll
    for (int s2 = 0; s2 < SEG; ++s2) {
        const float v = pm[t * PAD + s2];    // read: stride 21, conflict-free
        if (v > m) { m = v; idx = pi[t * PAD + s2]; }
    }

    const int q = base + t;
    const int w = q & 127;
    const int h = (q >> 7) & 127;
    const int a = (q >> 14) % 3;

    const float tx = txy[5 * t + 0], ty = txy[5 * t + 1];
    const float tw = txy[5 * t + 2], th = txy[5 * t + 3];
    const float ta = txy[5 * t + 4];
    const float aw = anchors[2 * a + 0];
    const float ah = anchors[2 * a + 1];

    const float px   = (sigmoidf_fast(tx) + (float)w) * 8.0f;   // STRIDE = 8
    const float py   = (sigmoidf_fast(ty) + (float)h) * 8.0f;
    const float pw   = __expf(tw) * aw;
    const float ph   = __expf(th) * ah;
    const float pdeg = sigmoidf_fast(ta) * 360.0f - 180.0f;     // sig*2pi-pi -> deg
    const float cf   = sigmoidf_fast(conf[q]) * sigmoidf_fast(m);

    // coalesced idx/conf stores
    out[NPOS * 5 + q] = (float)idx;
    out[NPOS * 6 + q] = cf;

    // stage p_xywha into own LDS row (only this thread touched these 5 words)
    txy[5 * t + 0] = px; txy[5 * t + 1] = py; txy[5 * t + 2] = pw;
    txy[5 * t + 3] = ph; txy[5 * t + 4] = pdeg;
    __syncthreads();

    // contiguous stores of the block's 640-float p_xywha tile
    float* __restrict__ og = out + (long long)base * 5;
    #pragma unroll
    for (int i = 0; i < 5; ++i) og[t + TPB * i] = txy[t + TPB * i];
}

extern "C" void kernel_launch(void* const* d_in, const int* in_sizes, int n_in,
                              void* d_out, int out_size, void* d_ws, size_t ws_size,
                              hipStream_t stream) {
    const float* t_xywha = (const float*)d_in[0];
    const float* conf    = (const float*)d_in[1];
    const float* cls     = (const float*)d_in[2];
    const float* anchors = (const float*)d_in[3];
    float* out = (float*)d_out;

    dim3 grid(NPOS / TPB);   // 6144 blocks
    dim3 block(TPB);
    yolo_decode_kernel<<<grid, block, 0, stream>>>(t_xywha, conf, cls, anchors, out);
}